// Round 8
// baseline (12.821 us; speedup 1.0000x reference)
//
#include <hip/hip_runtime.h>
#include <math.h>

// Problem constants (B=2, N_RES=512, N_ATOMS=4)
#define NPTS    2048
#define THREADS 512
#define PB      256                  // producer blocks (128 per batch)
#define KPB     8                    // circulant offsets per producer block
#define NS      4                    // consecutive i's per thread (i = 4*tid+s)
#define WIN     (NS + KPB - 1)       // 11-wide shared j-window per thread
#define PAD     (WIN - 1)            // 10 wrap-pad entries
#define ARR2    2060                 // float2 array length (2048 + pad, rounded)
#define ARRM    2060                 // mask array length
#define MAGIC   0xDEADBEEFu

typedef unsigned long long u64;

__device__ __forceinline__ bool pkt_ok(u64 v) {
    return (unsigned int)(v >> 32) == (((unsigned int)v) ^ MAGIC);
}

// b32-array swizzle: bijective per 32-block; identity on pad [2048,2079)
__device__ __forceinline__ int swz(int p)  { return p ^ ((p >> 5) & 31); }
// float2-array swizzle: spreads stride-4 lanes over all 16 bank-pairs;
// identity on pad [2048,2063)
__device__ __forceinline__ int swz2(int p) { return p ^ ((p >> 4) & 15); }

// Symmetry: total = 2*sum_{k=1..1023} T_k + T_1024 + diag, T_k = sum_i prox(i, i+k mod N)
__global__ __launch_bounds__(THREADS) void fused_sym_kernel(
    const float* __restrict__ pred, const float* __restrict__ nat,
    const int* __restrict__ mask, u64* __restrict__ ws_pkt,
    float* __restrict__ out, float inv_d0)
{
    __shared__ float2 A[ARR2];           // (px, py), swizzled via swz2
    __shared__ float2 Bv[ARR2];          // (pz, nx)
    __shared__ float2 Cv[ARR2];          // (ny, nz)
    __shared__ float  M[ARRM];           // mask as float, swizzled via swz
    __shared__ float  red[THREADS / 64];
    __shared__ float  aux0[THREADS / 64], aux1[THREADS / 64];

    const int bid  = blockIdx.x;
    const int tid  = threadIdx.x;
    const int lane = tid & 63;
    const int wid  = tid >> 6;

    if (bid < PB) {
        // ---------------- producer ----------------
        const int b   = bid >> 7;          // batch
        const int bib = bid & 127;         // block-in-batch
        const int k0  = 1 + bib * KPB;     // offsets k0..k0+7 (last block hits k=1024)

        const float* __restrict__ pb = pred + (size_t)(b * NPTS * 3);
        const float* __restrict__ nb = nat  + (size_t)(b * NPTS * 3);
        const int*   __restrict__ mb = mask + b * NPTS;

        // i-point coords straight from global: 12 consecutive floats per thread
        const float4* __restrict__ pb4 = (const float4*)pb;
        const float4* __restrict__ nb4 = (const float4*)nb;
        const int4*   __restrict__ mb4 = (const int4*)mb;
        const float4 p0 = pb4[3 * tid], p1 = pb4[3 * tid + 1], p2 = pb4[3 * tid + 2];
        const float4 n0 = nb4[3 * tid], n1 = nb4[3 * tid + 1], n2 = nb4[3 * tid + 2];
        const int4   mi4 = mb4[tid];

        const float pix[NS] = {p0.x, p0.w, p1.z, p2.y};
        const float piy[NS] = {p0.y, p1.x, p1.w, p2.z};
        const float piz[NS] = {p0.z, p1.y, p2.x, p2.w};
        const float nix[NS] = {n0.x, n0.w, n1.z, n2.y};
        const float niy[NS] = {n0.y, n1.x, n1.w, n2.z};
        const float niz[NS] = {n0.z, n1.y, n2.x, n2.w};
        const float mi[NS]  = {(float)(mi4.x != 0), (float)(mi4.y != 0),
                               (float)(mi4.z != 0), (float)(mi4.w != 0)};

        // stage batch into packed-float2 swizzled SoA (pad written inline)
        #pragma unroll
        for (int r = 0; r < 12; ++r) {
            const int idx = r * THREADS + tid;       // 0..6143, coalesced
            const int pt  = idx / 3;
            const int c   = idx - 3 * pt;
            const int sp  = swz2(pt);
            const float vp = pb[idx], vn = nb[idx];
            // pred: c0->A.x c1->A.y c2->B.x ; nat: c0->B.y c1->C.x c2->C.y
            if (c == 0)      { A[sp].x  = vp; Bv[sp].y = vn; }
            else if (c == 1) { A[sp].y  = vp; Cv[sp].x = vn; }
            else             { Bv[sp].x = vp; Cv[sp].y = vn; }
            if (pt < PAD) {                          // wrap-pad (swz2 identity there)
                const int pp = NPTS + pt;
                if (c == 0)      { A[pp].x  = vp; Bv[pp].y = vn; }
                else if (c == 1) { A[pp].y  = vp; Cv[pp].x = vn; }
                else             { Bv[pp].x = vp; Cv[pp].y = vn; }
            }
        }
        #pragma unroll
        for (int r = 0; r < 4; ++r) {
            const int p = r * THREADS + tid;
            const float mv = (float)(mb[p] != 0);
            M[swz(p)] = mv;
            if (p < PAD) M[NPTS + p] = mv;
        }
        __syncthreads();

        float acc[KPB] = {0.f, 0.f, 0.f, 0.f, 0.f, 0.f, 0.f, 0.f};
        const int jb = (4 * tid + k0) & (NPTS - 1);   // window base; jb+d <= 2057

        #pragma unroll
        for (int d = 0; d < WIN; ++d) {
            const int r  = jb + d;
            const int s2 = swz2(r);
            const float2 av = A[s2], bv = Bv[s2], cv = Cv[s2];
            const float  mj = M[swz(r)];
            const float qx = av.x, qy = av.y, qz = bv.x;
            const float ox = bv.y, oy = cv.x, oz = cv.y;
            const int smin = (d - (KPB - 1)) > 0 ? (d - (KPB - 1)) : 0;
            const int smax = d < (NS - 1) ? d : (NS - 1);
            #pragma unroll
            for (int s = smin; s <= smax; ++s) {      // kk = d - s in [0, KPB)
                const float dx = pix[s] - qx;
                const float dy = piy[s] - qy;
                const float dz = piz[s] - qz;
                const float pd = __builtin_amdgcn_sqrtf(dx * dx + dy * dy + dz * dz);
                const float ex = nix[s] - ox;
                const float ey = niy[s] - oy;
                const float ez = niz[s] - oz;
                const float nd = __builtin_amdgcn_sqrtf(ex * ex + ey * ey + ez * ez);
                const float u  = (pd - nd) * inv_d0;
                const float pr = __builtin_amdgcn_rcpf(fmaf(u, u, 1.0f));
                acc[d - s] = fmaf(mi[s] * mj, pr, acc[d - s]);
            }
        }

        // k = 1024 (kk==7 of the last block) counts once, not twice
        const float w7 = (bib == 127) ? 0.5f : 1.0f;
        float partial = acc[0] + acc[1] + acc[2] + acc[3]
                      + acc[4] + acc[5] + acc[6] + w7 * acc[7];

        for (int off = 32; off > 0; off >>= 1)
            partial += __shfl_down(partial, off, 64);
        if (lane == 0) red[wid] = partial;
        __syncthreads();
        if (tid == 0) {
            float p = 0.f;
            #pragma unroll
            for (int w = 0; w < THREADS / 64; ++w) p += red[w];
            const unsigned int pv = __float_as_uint(p);
            const u64 pkt = ((u64)(pv ^ MAGIC) << 32) | (u64)pv;
            __hip_atomic_store(&ws_pkt[bid], pkt,
                               __ATOMIC_RELAXED, __HIP_MEMORY_SCOPE_AGENT);
        }
    } else {
        // ---------------- finalizer ----------------
        int l0 = 0, l1 = 0;
        #pragma unroll
        for (int k = tid; k < NPTS; k += THREADS) {
            l0 += (mask[k]        != 0);
            l1 += (mask[NPTS + k] != 0);
        }

        float s = 0.f;
        if (tid < PB) {
            u64 v;
            do {
                v = __hip_atomic_load(&ws_pkt[tid],
                                      __ATOMIC_RELAXED, __HIP_MEMORY_SCOPE_AGENT);
            } while (!pkt_ok(v));
            s = __uint_as_float((unsigned int)v);
        }

        float f0 = (float)l0, f1 = (float)l1;
        for (int off = 32; off > 0; off >>= 1) {
            s  += __shfl_down(s,  off, 64);
            f0 += __shfl_down(f0, off, 64);
            f1 += __shfl_down(f1, off, 64);
        }
        if (lane == 0) { red[wid] = s; aux0[wid] = f0; aux1[wid] = f1; }
        __syncthreads();
        if (tid == 0) {
            float S = 0.f, C0 = 0.f, C1 = 0.f;
            #pragma unroll
            for (int w = 0; w < THREADS / 64; ++w) {
                S += red[w]; C0 += aux0[w]; C1 += aux1[w];
            }
            // total = 2*S_offdiag_half + diagonal (masked count), normalized
            out[0] = -(2.0f * S + C0 + C1) / (C0 * C0 + C1 * C1);
        }
    }
}

extern "C" void kernel_launch(void* const* d_in, const int* in_sizes, int n_in,
                              void* d_out, int out_size, void* d_ws, size_t ws_size,
                              hipStream_t stream) {
    const float* pred = (const float*)d_in[0];
    const float* nat  = (const float*)d_in[1];
    const int*   mask = (const int*)d_in[2];
    float* out = (float*)d_out;
    u64*   ws_pkt = (u64*)d_ws;

    // d0 = 1.24 * (512 - 15)^(1/3) - 1.8  (host-side pure math, capture-safe)
    const double d0 = 1.24 * cbrt(512.0 - 15.0) - 1.8;
    const float inv_d0 = (float)(1.0 / d0);

    fused_sym_kernel<<<PB + 1, THREADS, 0, stream>>>(
        pred, nat, mask, ws_pkt, out, inv_d0);
}

// Round 9
// 12.415 us; speedup vs baseline: 1.0327x; 1.0327x over previous
//
#include <hip/hip_runtime.h>
#include <math.h>

// Problem constants (B=2, N_RES=512, N_ATOMS=4)
#define NPTS    2048
#define THREADS 512
#define PB      256                  // producer blocks (128 per batch)
#define KPB     8                    // circulant offsets per producer block
#define NS      4                    // consecutive i's per thread (i = 4*tid+s)
#define WIN     (NS + KPB - 1)       // 11-wide shared j-window per thread
#define PAD     (WIN - 1)            // 10 wrap-pad entries
#define ARR     2064                 // LDS array length (2048 + pad + swizzle slack)
#define MAGIC   0xDEADBEEFu

typedef unsigned long long u64;

__device__ __forceinline__ bool pkt_ok(u64 v) {
    return (unsigned int)(v >> 32) == (((unsigned int)v) ^ MAGIC);
}

// Per-width XOR swizzles (bijective; applied consistently on write AND read):
__device__ __forceinline__ int s4i(int p) { return p ^ ((p >> 3) & 7); }   // float4 bank-quad
__device__ __forceinline__ int s2i(int p) { return p ^ ((p >> 4) & 15); }  // float2 bank-pair
__device__ __forceinline__ int s1i(int p) { return p ^ ((p >> 5) & 31); }  // float bank

// Symmetry: total = 2*sum_{k=1..1023} T_k + T_1024 + diag, T_k = sum_i prox(i, i+k mod N)
__global__ __launch_bounds__(THREADS) void fused_sym_kernel(
    const float* __restrict__ pred, const float* __restrict__ nat,
    const int* __restrict__ mask, u64* __restrict__ ws_pkt,
    float* __restrict__ out, float inv_d0)
{
    __shared__ float4 F4[ARR];           // {px, py, pz, nx}
    __shared__ float2 F2[ARR];           // {ny, nz}
    __shared__ float  FM[ARR];           // mask as float
    __shared__ float  red[THREADS / 64];
    __shared__ float  aux0[THREADS / 64], aux1[THREADS / 64];

    const int bid  = blockIdx.x;
    const int tid  = threadIdx.x;
    const int lane = tid & 63;
    const int wid  = tid >> 6;

    if (bid < PB) {
        // ---------------- producer ----------------
        const int b   = bid >> 7;          // batch
        const int bib = bid & 127;         // block-in-batch
        const int k0  = 1 + bib * KPB;     // offsets k0..k0+7 (last block hits k=1024)

        const float* __restrict__ pb = pred + (size_t)(b * NPTS * 3);
        const float* __restrict__ nb = nat  + (size_t)(b * NPTS * 3);
        const int*   __restrict__ mb = mask + b * NPTS;

        // this thread's 4 consecutive points = 12 consecutive floats per tensor
        const float4* __restrict__ pb4 = (const float4*)pb;
        const float4* __restrict__ nb4 = (const float4*)nb;
        const int4*   __restrict__ mb4 = (const int4*)mb;
        const float4 p0 = pb4[3 * tid], p1 = pb4[3 * tid + 1], p2 = pb4[3 * tid + 2];
        const float4 n0 = nb4[3 * tid], n1 = nb4[3 * tid + 1], n2 = nb4[3 * tid + 2];
        const int4   mi4 = mb4[tid];

        const float pix[NS] = {p0.x, p0.w, p1.z, p2.y};
        const float piy[NS] = {p0.y, p1.x, p1.w, p2.z};
        const float piz[NS] = {p0.z, p1.y, p2.x, p2.w};
        const float nix[NS] = {n0.x, n0.w, n1.z, n2.y};
        const float niy[NS] = {n0.y, n1.x, n1.w, n2.z};
        const float niz[NS] = {n0.z, n1.y, n2.x, n2.w};
        const float mi[NS]  = {(float)(mi4.x != 0), (float)(mi4.y != 0),
                               (float)(mi4.z != 0), (float)(mi4.w != 0)};

        // branch-free staging: each thread writes its own 4 points from registers
        #pragma unroll
        for (int s = 0; s < NS; ++s) {
            const int p = 4 * tid + s;
            F4[s4i(p)] = make_float4(pix[s], piy[s], piz[s], nix[s]);
            F2[s2i(p)] = make_float2(niy[s], niz[s]);
            FM[s1i(p)] = mi[s];
        }
        if (4 * tid < PAD) {                 // only threads 0..2 duplicate the wrap-pad
            #pragma unroll
            for (int s = 0; s < NS; ++s) {
                const int p = 4 * tid + s;
                if (p < PAD) {
                    F4[s4i(NPTS + p)] = make_float4(pix[s], piy[s], piz[s], nix[s]);
                    F2[s2i(NPTS + p)] = make_float2(niy[s], niz[s]);
                    FM[s1i(NPTS + p)] = mi[s];
                }
            }
        }
        __syncthreads();

        float acc[KPB] = {0.f, 0.f, 0.f, 0.f, 0.f, 0.f, 0.f, 0.f};
        const int jb = (4 * tid + k0) & (NPTS - 1);   // window base; jb+d <= 2057

        #pragma unroll
        for (int d = 0; d < WIN; ++d) {
            const int r = jb + d;
            const float4 f4 = F4[s4i(r)];
            const float2 f2 = F2[s2i(r)];
            const float  mj = FM[s1i(r)];
            const float qx = f4.x, qy = f4.y, qz = f4.z;
            const float ox = f4.w, oy = f2.x, oz = f2.y;
            const int smin = (d - (KPB - 1)) > 0 ? (d - (KPB - 1)) : 0;
            const int smax = d < (NS - 1) ? d : (NS - 1);
            #pragma unroll
            for (int s = smin; s <= smax; ++s) {      // kk = d - s in [0, KPB)
                const float dx = pix[s] - qx;
                const float dy = piy[s] - qy;
                const float dz = piz[s] - qz;
                const float pd = __builtin_amdgcn_sqrtf(dx * dx + dy * dy + dz * dz);
                const float ex = nix[s] - ox;
                const float ey = niy[s] - oy;
                const float ez = niz[s] - oz;
                const float nd = __builtin_amdgcn_sqrtf(ex * ex + ey * ey + ez * ez);
                const float u  = (pd - nd) * inv_d0;
                const float pr = __builtin_amdgcn_rcpf(fmaf(u, u, 1.0f));
                acc[d - s] = fmaf(mi[s] * mj, pr, acc[d - s]);
            }
        }

        // k = 1024 (kk==7 of the last block) counts once, not twice
        const float w7 = (bib == 127) ? 0.5f : 1.0f;
        float partial = acc[0] + acc[1] + acc[2] + acc[3]
                      + acc[4] + acc[5] + acc[6] + w7 * acc[7];

        for (int off = 32; off > 0; off >>= 1)
            partial += __shfl_down(partial, off, 64);
        if (lane == 0) red[wid] = partial;
        __syncthreads();
        if (tid == 0) {
            float p = 0.f;
            #pragma unroll
            for (int w = 0; w < THREADS / 64; ++w) p += red[w];
            const unsigned int pv = __float_as_uint(p);
            const u64 pkt = ((u64)(pv ^ MAGIC) << 32) | (u64)pv;
            __hip_atomic_store(&ws_pkt[bid], pkt,
                               __ATOMIC_RELAXED, __HIP_MEMORY_SCOPE_AGENT);
        }
    } else {
        // ---------------- finalizer ----------------
        int l0 = 0, l1 = 0;
        #pragma unroll
        for (int k = tid; k < NPTS; k += THREADS) {
            l0 += (mask[k]        != 0);
            l1 += (mask[NPTS + k] != 0);
        }

        float s = 0.f;
        if (tid < PB) {
            u64 v;
            do {
                v = __hip_atomic_load(&ws_pkt[tid],
                                      __ATOMIC_RELAXED, __HIP_MEMORY_SCOPE_AGENT);
            } while (!pkt_ok(v));
            s = __uint_as_float((unsigned int)v);
        }

        float f0 = (float)l0, f1 = (float)l1;
        for (int off = 32; off > 0; off >>= 1) {
            s  += __shfl_down(s,  off, 64);
            f0 += __shfl_down(f0, off, 64);
            f1 += __shfl_down(f1, off, 64);
        }
        if (lane == 0) { red[wid] = s; aux0[wid] = f0; aux1[wid] = f1; }
        __syncthreads();
        if (tid == 0) {
            float S = 0.f, C0 = 0.f, C1 = 0.f;
            #pragma unroll
            for (int w = 0; w < THREADS / 64; ++w) {
                S += red[w]; C0 += aux0[w]; C1 += aux1[w];
            }
            // total = 2*S_offdiag_half + diagonal (masked count), normalized
            out[0] = -(2.0f * S + C0 + C1) / (C0 * C0 + C1 * C1);
        }
    }
}

extern "C" void kernel_launch(void* const* d_in, const int* in_sizes, int n_in,
                              void* d_out, int out_size, void* d_ws, size_t ws_size,
                              hipStream_t stream) {
    const float* pred = (const float*)d_in[0];
    const float* nat  = (const float*)d_in[1];
    const int*   mask = (const int*)d_in[2];
    float* out = (float*)d_out;
    u64*   ws_pkt = (u64*)d_ws;

    // d0 = 1.24 * (512 - 15)^(1/3) - 1.8  (host-side pure math, capture-safe)
    const double d0 = 1.24 * cbrt(512.0 - 15.0) - 1.8;
    const float inv_d0 = (float)(1.0 / d0);

    fused_sym_kernel<<<PB + 1, THREADS, 0, stream>>>(
        pred, nat, mask, ws_pkt, out, inv_d0);
}

// Round 10
// 11.565 us; speedup vs baseline: 1.1086x; 1.0735x over previous
//
#include <hip/hip_runtime.h>
#include <math.h>

// Problem constants (B=2, N_RES=512, N_ATOMS=4)
#define NPTS    2048
#define THREADS 512
#define PB      256                  // producer blocks = grid size = #CUs (no straggler)
#define KPB     8                    // circulant offsets per producer block
#define NS      4                    // consecutive i's per thread (i = 4*tid+s)
#define WIN     (NS + KPB - 1)       // 11-wide shared j-window per thread
#define ARR     2060                 // padded SoA array length (2048 + 10 pad)
#define MAGIC   0xDEADBEEFu

typedef unsigned long long u64;

__device__ __forceinline__ bool pkt_ok(u64 v) {
    return (unsigned int)(v >> 32) == (((unsigned int)v) ^ MAGIC);
}

// XOR bank-swizzle: bijective within each 32-word block; identity on [2048,2079)
__device__ __forceinline__ int swz(int p) { return p ^ ((p >> 5) & 31); }

// Symmetry: total = 2*sum_{k=1..1023} T_k + T_1024 + diag, T_k = sum_i prox(i, i+k mod N)
__global__ __launch_bounds__(THREADS) void fused_sym_kernel(
    const float* __restrict__ pred, const float* __restrict__ nat,
    const int* __restrict__ mask, u64* __restrict__ ws_pkt,
    float* __restrict__ out, float inv_d0)
{
    __shared__ float lds[7 * ARR];       // SoA: px,py,pz,nx,ny,nz,m (swizzled)
    __shared__ float red[THREADS / 64];
    __shared__ float aux0[THREADS / 64], aux1[THREADS / 64];

    const int bid  = blockIdx.x;
    const int tid  = threadIdx.x;
    const int lane = tid & 63;
    const int wid  = tid >> 6;

    // ---------------- producer (ALL 256 blocks) ----------------
    const int b   = bid >> 7;          // batch
    const int bib = bid & 127;         // block-in-batch
    const int k0  = 1 + bib * KPB;     // offsets k0..k0+7 (last block hits k=1024)

    const float* __restrict__ pb = pred + (size_t)(b * NPTS * 3);
    const float* __restrict__ nb = nat  + (size_t)(b * NPTS * 3);
    const int*   __restrict__ mb = mask + b * NPTS;

    // stage batch into LDS, swizzled SoA layout lds[c*ARR + swz(pt)]
    #pragma unroll
    for (int r = 0; r < 12; ++r) {
        const int idx = r * THREADS + tid;       // 0..6143, coalesced
        const int pt  = idx / 3;
        const int c   = idx - 3 * pt;
        const int sp  = swz(pt);
        lds[c * ARR + sp]       = pb[idx];
        lds[(3 + c) * ARR + sp] = nb[idx];
    }
    #pragma unroll
    for (int r = 0; r < 4; ++r) {
        const int p = r * THREADS + tid;
        lds[6 * ARR + swz(p)] = (float)(mb[p] != 0);
    }
    __syncthreads();
    if (tid < 7 * (WIN - 1)) {                   // wrap-pad 10 entries per array
        const int c = tid / (WIN - 1), e = tid % (WIN - 1);
        lds[c * ARR + NPTS + e] = lds[c * ARR + e];  // swz(e)==e for e<32
    }
    __syncthreads();

    // hoist this thread's 4 consecutive i-points into registers
    float pix[NS], piy[NS], piz[NS], nix[NS], niy[NS], niz[NS], mi[NS];
    #pragma unroll
    for (int s = 0; s < NS; ++s) {
        const int si = swz(4 * tid + s);
        pix[s] = lds[0 * ARR + si]; piy[s] = lds[1 * ARR + si]; piz[s] = lds[2 * ARR + si];
        nix[s] = lds[3 * ARR + si]; niy[s] = lds[4 * ARR + si]; niz[s] = lds[5 * ARR + si];
        mi[s]  = lds[6 * ARR + si];
    }

    float acc[KPB] = {0.f, 0.f, 0.f, 0.f, 0.f, 0.f, 0.f, 0.f};
    const int jb = (4 * tid + k0) & (NPTS - 1);   // window base; jb+d <= 2057

    #pragma unroll
    for (int d = 0; d < WIN; ++d) {
        const int ji = swz(jb + d);               // identity on pad region
        const float qx = lds[0 * ARR + ji], qy = lds[1 * ARR + ji], qz = lds[2 * ARR + ji];
        const float ox = lds[3 * ARR + ji], oy = lds[4 * ARR + ji], oz = lds[5 * ARR + ji];
        const float mj = lds[6 * ARR + ji];
        const int smin = (d - (KPB - 1)) > 0 ? (d - (KPB - 1)) : 0;
        const int smax = d < (NS - 1) ? d : (NS - 1);
        #pragma unroll
        for (int s = smin; s <= smax; ++s) {      // kk = d - s in [0, KPB)
            const float dx = pix[s] - qx;
            const float dy = piy[s] - qy;
            const float dz = piz[s] - qz;
            const float pd = __builtin_amdgcn_sqrtf(dx * dx + dy * dy + dz * dz);
            const float ex = nix[s] - ox;
            const float ey = niy[s] - oy;
            const float ez = niz[s] - oz;
            const float nd = __builtin_amdgcn_sqrtf(ex * ex + ey * ey + ez * ez);
            const float u  = (pd - nd) * inv_d0;
            const float pr = __builtin_amdgcn_rcpf(fmaf(u, u, 1.0f));
            acc[d - s] = fmaf(mi[s] * mj, pr, acc[d - s]);
        }
    }

    // k = 1024 (kk==7 of the last block) counts once, not twice
    const float w7 = (bib == 127) ? 0.5f : 1.0f;
    float partial = acc[0] + acc[1] + acc[2] + acc[3]
                  + acc[4] + acc[5] + acc[6] + w7 * acc[7];

    for (int off = 32; off > 0; off >>= 1)
        partial += __shfl_down(partial, off, 64);
    if (lane == 0) red[wid] = partial;
    __syncthreads();
    if (tid == 0) {
        float p = 0.f;
        #pragma unroll
        for (int w = 0; w < THREADS / 64; ++w) p += red[w];
        const unsigned int pv = __float_as_uint(p);
        const u64 pkt = ((u64)(pv ^ MAGIC) << 32) | (u64)pv;
        __hip_atomic_store(&ws_pkt[bid], pkt,
                           __ATOMIC_RELAXED, __HIP_MEMORY_SCOPE_AGENT);
    }

    // ---------------- finalizer tail (block 0 only) ----------------
    if (bid == 0) {
        __syncthreads();                          // red[] reuse + packet store done

        int l0 = 0, l1 = 0;
        #pragma unroll
        for (int k = tid; k < NPTS; k += THREADS) {
            l0 += (mask[k]        != 0);
            l1 += (mask[NPTS + k] != 0);
        }

        float s = 0.f;
        if (tid < PB) {                           // one packet per thread (waves 0-3)
            u64 v;
            do {
                v = __hip_atomic_load(&ws_pkt[tid],
                                      __ATOMIC_RELAXED, __HIP_MEMORY_SCOPE_AGENT);
            } while (!pkt_ok(v));
            s = __uint_as_float((unsigned int)v);
        }

        float f0 = (float)l0, f1 = (float)l1;
        for (int off = 32; off > 0; off >>= 1) {
            s  += __shfl_down(s,  off, 64);
            f0 += __shfl_down(f0, off, 64);
            f1 += __shfl_down(f1, off, 64);
        }
        if (lane == 0) { red[wid] = s; aux0[wid] = f0; aux1[wid] = f1; }
        __syncthreads();
        if (tid == 0) {
            float S = 0.f, C0 = 0.f, C1 = 0.f;
            #pragma unroll
            for (int w = 0; w < THREADS / 64; ++w) {
                S += red[w]; C0 += aux0[w]; C1 += aux1[w];
            }
            // total = 2*S_offdiag_half + diagonal (masked count), normalized
            out[0] = -(2.0f * S + C0 + C1) / (C0 * C0 + C1 * C1);
        }
    }
}

extern "C" void kernel_launch(void* const* d_in, const int* in_sizes, int n_in,
                              void* d_out, int out_size, void* d_ws, size_t ws_size,
                              hipStream_t stream) {
    const float* pred = (const float*)d_in[0];
    const float* nat  = (const float*)d_in[1];
    const int*   mask = (const int*)d_in[2];
    float* out = (float*)d_out;
    u64*   ws_pkt = (u64*)d_ws;

    // d0 = 1.24 * (512 - 15)^(1/3) - 1.8  (host-side pure math, capture-safe)
    const double d0 = 1.24 * cbrt(512.0 - 15.0) - 1.8;
    const float inv_d0 = (float)(1.0 / d0);

    fused_sym_kernel<<<PB, THREADS, 0, stream>>>(
        pred, nat, mask, ws_pkt, out, inv_d0);
}

// Round 11
// 10.520 us; speedup vs baseline: 1.2188x; 1.0993x over previous
//
#include <hip/hip_runtime.h>
#include <math.h>

// Problem constants (B=2, N_RES=512, N_ATOMS=4)
#define NPTS    2048
#define THREADS 1024                 // 16 waves/block -> 4 waves/SIMD
#define PB      256                  // producer blocks (128 per batch)
#define KPB     8                    // circulant offsets per producer block
#define NS      2                    // consecutive i's per thread (i = 2*tid+s)
#define WIN     (NS + KPB - 1)       // 9-wide shared j-window per thread
#define PAD     (WIN - 1)            // 8 wrap-pad entries
#define ARR     2056                 // padded SoA array length (2048 + 8)
#define NW      (THREADS / 64)       // 16 waves
#define MAGIC   0xDEADBEEFu

typedef unsigned long long u64;

__device__ __forceinline__ bool pkt_ok(u64 v) {
    return (unsigned int)(v >> 32) == (((unsigned int)v) ^ MAGIC);
}

// XOR bank-swizzle: bijective within each 32-word block; identity on [2048,2080)
__device__ __forceinline__ int swz(int p) { return p ^ ((p >> 5) & 31); }

// Symmetry: total = 2*sum_{k=1..1023} T_k + T_1024 + diag, T_k = sum_i prox(i, i+k mod N)
__global__ __launch_bounds__(THREADS) void fused_sym_kernel(
    const float* __restrict__ pred, const float* __restrict__ nat,
    const int* __restrict__ mask, u64* __restrict__ ws_pkt,
    float* __restrict__ out, float inv_d0)
{
    __shared__ float lds[7 * ARR];       // SoA: px,py,pz,nx,ny,nz,m (swizzled)
    __shared__ float red[NW];
    __shared__ float aux0[NW], aux1[NW];

    const int bid  = blockIdx.x;
    const int tid  = threadIdx.x;
    const int lane = tid & 63;
    const int wid  = tid >> 6;

    if (bid < PB) {
        // ---------------- producer ----------------
        const int b   = bid >> 7;          // batch
        const int bib = bid & 127;         // block-in-batch
        const int k0  = 1 + bib * KPB;     // offsets k0..k0+7 (last block hits k=1024)

        const float* __restrict__ pb = pred + (size_t)(b * NPTS * 3);
        const float* __restrict__ nb = nat  + (size_t)(b * NPTS * 3);
        const int*   __restrict__ mb = mask + b * NPTS;

        // stage batch into LDS (swizzled SoA), wrap-pad written inline
        #pragma unroll
        for (int r = 0; r < 6; ++r) {
            const int idx = r * THREADS + tid;       // 0..6143, coalesced
            const int pt  = idx / 3;
            const int c   = idx - 3 * pt;
            const int sp  = swz(pt);
            const float vp = pb[idx], vn = nb[idx];
            lds[c * ARR + sp]       = vp;
            lds[(3 + c) * ARR + sp] = vn;
            if (pt < PAD) {                          // swz identity on pad region
                lds[c * ARR + NPTS + pt]       = vp;
                lds[(3 + c) * ARR + NPTS + pt] = vn;
            }
        }
        #pragma unroll
        for (int r = 0; r < 2; ++r) {
            const int p = r * THREADS + tid;
            const float mv = (float)(mb[p] != 0);
            lds[6 * ARR + swz(p)] = mv;
            if (p < PAD) lds[6 * ARR + NPTS + p] = mv;
        }
        __syncthreads();

        // hoist this thread's 2 consecutive i-points into registers
        float pix[NS], piy[NS], piz[NS], nix[NS], niy[NS], niz[NS], mi[NS];
        #pragma unroll
        for (int s = 0; s < NS; ++s) {
            const int si = swz(2 * tid + s);
            pix[s] = lds[0 * ARR + si]; piy[s] = lds[1 * ARR + si]; piz[s] = lds[2 * ARR + si];
            nix[s] = lds[3 * ARR + si]; niy[s] = lds[4 * ARR + si]; niz[s] = lds[5 * ARR + si];
            mi[s]  = lds[6 * ARR + si];
        }

        float acc[KPB] = {0.f, 0.f, 0.f, 0.f, 0.f, 0.f, 0.f, 0.f};
        const int jb = (2 * tid + k0) & (NPTS - 1);   // window base; jb+d <= 2055

        #pragma unroll
        for (int d = 0; d < WIN; ++d) {
            const int ji = swz(jb + d);               // identity on pad region
            const float qx = lds[0 * ARR + ji], qy = lds[1 * ARR + ji], qz = lds[2 * ARR + ji];
            const float ox = lds[3 * ARR + ji], oy = lds[4 * ARR + ji], oz = lds[5 * ARR + ji];
            const float mj = lds[6 * ARR + ji];
            const int smin = (d - (KPB - 1)) > 0 ? (d - (KPB - 1)) : 0;
            const int smax = d < (NS - 1) ? d : (NS - 1);
            #pragma unroll
            for (int s = smin; s <= smax; ++s) {      // kk = d - s in [0, KPB)
                const float dx = pix[s] - qx;
                const float dy = piy[s] - qy;
                const float dz = piz[s] - qz;
                const float pd = __builtin_amdgcn_sqrtf(dx * dx + dy * dy + dz * dz);
                const float ex = nix[s] - ox;
                const float ey = niy[s] - oy;
                const float ez = niz[s] - oz;
                const float nd = __builtin_amdgcn_sqrtf(ex * ex + ey * ey + ez * ez);
                const float u  = (pd - nd) * inv_d0;
                const float pr = __builtin_amdgcn_rcpf(fmaf(u, u, 1.0f));
                acc[d - s] = fmaf(mi[s] * mj, pr, acc[d - s]);
            }
        }

        // k = 1024 (kk==7 of the last block) counts once, not twice
        const float w7 = (bib == 127) ? 0.5f : 1.0f;
        float partial = acc[0] + acc[1] + acc[2] + acc[3]
                      + acc[4] + acc[5] + acc[6] + w7 * acc[7];

        for (int off = 32; off > 0; off >>= 1)
            partial += __shfl_down(partial, off, 64);
        if (lane == 0) red[wid] = partial;
        __syncthreads();
        if (tid == 0) {
            float p = 0.f;
            #pragma unroll
            for (int w = 0; w < NW; ++w) p += red[w];
            const unsigned int pv = __float_as_uint(p);
            const u64 pkt = ((u64)(pv ^ MAGIC) << 32) | (u64)pv;
            __hip_atomic_store(&ws_pkt[bid], pkt,
                               __ATOMIC_RELAXED, __HIP_MEMORY_SCOPE_AGENT);
        }
    } else {
        // ---------------- finalizer (dedicated 257th block) ----------------
        int l0 = 0, l1 = 0;
        #pragma unroll
        for (int k = tid; k < NPTS; k += THREADS) {
            l0 += (mask[k]        != 0);
            l1 += (mask[NPTS + k] != 0);
        }

        float s = 0.f;
        if (tid < PB) {
            u64 v;
            do {
                v = __hip_atomic_load(&ws_pkt[tid],
                                      __ATOMIC_RELAXED, __HIP_MEMORY_SCOPE_AGENT);
            } while (!pkt_ok(v));
            s = __uint_as_float((unsigned int)v);
        }

        float f0 = (float)l0, f1 = (float)l1;
        for (int off = 32; off > 0; off >>= 1) {
            s  += __shfl_down(s,  off, 64);
            f0 += __shfl_down(f0, off, 64);
            f1 += __shfl_down(f1, off, 64);
        }
        if (lane == 0) { red[wid] = s; aux0[wid] = f0; aux1[wid] = f1; }
        __syncthreads();
        if (tid == 0) {
            float S = 0.f, C0 = 0.f, C1 = 0.f;
            #pragma unroll
            for (int w = 0; w < NW; ++w) {
                S += red[w]; C0 += aux0[w]; C1 += aux1[w];
            }
            // total = 2*S_offdiag_half + diagonal (masked count), normalized
            out[0] = -(2.0f * S + C0 + C1) / (C0 * C0 + C1 * C1);
        }
    }
}

extern "C" void kernel_launch(void* const* d_in, const int* in_sizes, int n_in,
                              void* d_out, int out_size, void* d_ws, size_t ws_size,
                              hipStream_t stream) {
    const float* pred = (const float*)d_in[0];
    const float* nat  = (const float*)d_in[1];
    const int*   mask = (const int*)d_in[2];
    float* out = (float*)d_out;
    u64*   ws_pkt = (u64*)d_ws;

    // d0 = 1.24 * (512 - 15)^(1/3) - 1.8  (host-side pure math, capture-safe)
    const double d0 = 1.24 * cbrt(512.0 - 15.0) - 1.8;
    const float inv_d0 = (float)(1.0 / d0);

    fused_sym_kernel<<<PB + 1, THREADS, 0, stream>>>(
        pred, nat, mask, ws_pkt, out, inv_d0);
}